// Round 1
// baseline (460.796 us; speedup 1.0000x reference)
//
#include <hip/hip_runtime.h>
#include <hip/hip_bf16.h>
#include <math.h>

constexpr int NN   = 8192;   // nodes
constexpr int FIN  = 512;    // input features
constexpr int HC   = 256;    // concat hidden = K(2) * H(128)
constexpr int COUT = 16;     // classes
constexpr int MAXD = 128;    // neighbor cap (avg deg ~33, max ~60)

__device__ __forceinline__ float lrelu(float x) { return x > 0.f ? x : 0.2f * x; }

// ---------------------------------------------------------------------------
// Detect adjacency element width. adj includes the identity, so the diagonal
// is all-ones. If reading as int32 at diag positions gives 1 (int layout) or
// 0x3f800000 (float layout) for ALL 64 probes -> 4-byte elements, else 1-byte.
// Probe rows are kept < 2048 so int32 indexing stays in-bounds even if the
// buffer is actually uint8 (67 MB).
// ---------------------------------------------------------------------------
__global__ __launch_bounds__(64) void detect_kernel(const int* __restrict__ adj32,
                                                    int* __restrict__ flag) {
  int lane = threadIdx.x;
  size_t idx = (size_t)(lane * 32) * (size_t)(NN + 1);
  int v = adj32[idx];
  bool four = (v == 1) || (v == 0x3f800000);
  unsigned long long b = __ballot(four);
  if (lane == 0) flag[0] = (b == ~0ull) ? 1 : 0;
}

// ---------------------------------------------------------------------------
// Dense adjacency row scan -> CSR-ish neighbor lists (unordered; softmax sum
// order only perturbs fp32 at ~1e-7). One block per row.
// ---------------------------------------------------------------------------
__global__ __launch_bounds__(256) void build_csr(const void* __restrict__ adj,
                                                 const int* __restrict__ flag,
                                                 int* __restrict__ nbr,
                                                 int* __restrict__ cnt) {
  __shared__ int scnt;
  int i = blockIdx.x;
  if (threadIdx.x == 0) scnt = 0;
  __syncthreads();
  int* row_out = nbr + (size_t)i * MAXD;
  if (flag[0]) {  // 4-byte elements (int32 or float32: nonzero bits == edge)
    const int4* row = reinterpret_cast<const int4*>((const int*)adj + (size_t)i * NN);
#pragma unroll
    for (int rep = 0; rep < 8; ++rep) {
      int vi = rep * 256 + threadIdx.x;
      int4 v = row[vi];
      int base = vi * 4;
      if (v.x) { int p = atomicAdd(&scnt, 1); if (p < MAXD) row_out[p] = base; }
      if (v.y) { int p = atomicAdd(&scnt, 1); if (p < MAXD) row_out[p] = base + 1; }
      if (v.z) { int p = atomicAdd(&scnt, 1); if (p < MAXD) row_out[p] = base + 2; }
      if (v.w) { int p = atomicAdd(&scnt, 1); if (p < MAXD) row_out[p] = base + 3; }
    }
  } else {  // 1-byte elements
    const uint4* row = reinterpret_cast<const uint4*>((const unsigned char*)adj + (size_t)i * NN);
#pragma unroll
    for (int rep = 0; rep < 2; ++rep) {
      int vi = rep * 256 + threadIdx.x;
      uint4 v = row[vi];
      int base = vi * 16;
      unsigned w[4] = {v.x, v.y, v.z, v.w};
#pragma unroll
      for (int q = 0; q < 4; ++q)
#pragma unroll
        for (int b = 0; b < 4; ++b)
          if ((w[q] >> (8 * b)) & 0xffu) {
            int p = atomicAdd(&scnt, 1);
            if (p < MAXD) row_out[p] = base + q * 4 + b;
          }
    }
  }
  __syncthreads();
  if (threadIdx.x == 0) cnt[i] = scnt < MAXD ? scnt : MAXD;
}

// ---------------------------------------------------------------------------
// Repack W1 [K=2][F=512][H=128] -> Wc [F=512][K*H=256] so layer-1 GEMM output
// lands directly in concat layout [n][k*128+h].
// ---------------------------------------------------------------------------
__global__ __launch_bounds__(256) void repack_w1(const float* __restrict__ W1,
                                                 float* __restrict__ Wc) {
  int idx = blockIdx.x * 256 + threadIdx.x;   // k*65536 + f*128 + h
  int h = idx & 127;
  int f = (idx >> 7) & 511;
  int k = idx >> 16;
  Wc[f * HC + k * 128 + h] = W1[idx];
}

// ---------------------------------------------------------------------------
// H[8192][256] = X[8192][512] @ Wc[512][256]. fp32, 64x64 tiles, 4x4/thread.
// ---------------------------------------------------------------------------
__global__ __launch_bounds__(256) void gemm1_kernel(const float* __restrict__ X,
                                                    const float* __restrict__ B,
                                                    float* __restrict__ Hout) {
  __shared__ float As[16][64];
  __shared__ float Bs[16][64];
  int tid = threadIdx.x;
  int brow = blockIdx.x * 64;
  int bcol = blockIdx.y * 64;
  int tr = (tid >> 4) * 4;
  int tc = (tid & 15) * 4;
  float acc[4][4] = {};
  int lr = tid >> 2;         // A-load: row 0..63
  int lk = (tid & 3) * 4;    // A-load: k offset 0,4,8,12
  int bk = tid >> 4;         // B-load: k row 0..15
  int bc = (tid & 15) * 4;   // B-load: col
  for (int k0 = 0; k0 < FIN; k0 += 16) {
    float4 av = *reinterpret_cast<const float4*>(X + (size_t)(brow + lr) * FIN + k0 + lk);
    As[lk + 0][lr] = av.x; As[lk + 1][lr] = av.y;
    As[lk + 2][lr] = av.z; As[lk + 3][lr] = av.w;
    float4 bv = *reinterpret_cast<const float4*>(B + (size_t)(k0 + bk) * HC + bcol + bc);
    *reinterpret_cast<float4*>(&Bs[bk][bc]) = bv;
    __syncthreads();
#pragma unroll
    for (int kk = 0; kk < 16; ++kk) {
      float a0 = As[kk][tr + 0], a1 = As[kk][tr + 1];
      float a2 = As[kk][tr + 2], a3 = As[kk][tr + 3];
      float4 b4 = *reinterpret_cast<const float4*>(&Bs[kk][tc]);
      acc[0][0] += a0 * b4.x; acc[0][1] += a0 * b4.y; acc[0][2] += a0 * b4.z; acc[0][3] += a0 * b4.w;
      acc[1][0] += a1 * b4.x; acc[1][1] += a1 * b4.y; acc[1][2] += a1 * b4.z; acc[1][3] += a1 * b4.w;
      acc[2][0] += a2 * b4.x; acc[2][1] += a2 * b4.y; acc[2][2] += a2 * b4.z; acc[2][3] += a2 * b4.w;
      acc[3][0] += a3 * b4.x; acc[3][1] += a3 * b4.y; acc[3][2] += a3 * b4.z; acc[3][3] += a3 * b4.w;
    }
    __syncthreads();
  }
#pragma unroll
  for (int r = 0; r < 4; ++r) {
    float4 o = make_float4(acc[r][0], acc[r][1], acc[r][2], acc[r][3]);
    *reinterpret_cast<float4*>(Hout + (size_t)(brow + tr + r) * HC + bcol + tc) = o;
  }
}

// ---------------------------------------------------------------------------
// f_src[k][n] = dot(H[n][k*128: (k+1)*128], a_src[k]); same for f_dst.
// One wave per node: 256 features over 64 lanes (4 each), shuffle-reduce.
// ---------------------------------------------------------------------------
__global__ __launch_bounds__(256) void f1_kernel(const float* __restrict__ H,
                                                 const float* __restrict__ a_src,
                                                 const float* __restrict__ a_dst,
                                                 float* __restrict__ fs,
                                                 float* __restrict__ fd) {
  int wave = threadIdx.x >> 6, lane = threadIdx.x & 63;
  int n = blockIdx.x * 4 + wave;
  const float* hr = H + (size_t)n * HC;
  float h0 = hr[lane], h1 = hr[lane + 64], h2 = hr[lane + 128], h3 = hr[lane + 192];
  float s0 = h0 * a_src[lane] + h1 * a_src[lane + 64];
  float s1 = h2 * a_src[lane + 128] + h3 * a_src[lane + 192];
  float d0 = h0 * a_dst[lane] + h1 * a_dst[lane + 64];
  float d1 = h2 * a_dst[lane + 128] + h3 * a_dst[lane + 192];
#pragma unroll
  for (int off = 32; off > 0; off >>= 1) {
    s0 += __shfl_xor(s0, off);
    s1 += __shfl_xor(s1, off);
    d0 += __shfl_xor(d0, off);
    d1 += __shfl_xor(d1, off);
  }
  if (lane == 0) {
    fs[n] = s0; fs[NN + n] = s1;
    fd[n] = d0; fd[NN + n] = d1;
  }
}

// ---------------------------------------------------------------------------
// Layer-1 sparse attention. One block (256 thr) per row i.
// Phase A: edge scores + masked softmax (exact vs dense: exp(NEG_INF-m)==0).
// Phase B: thread c accumulates sum_j att[k(c)][j] * H[j][c]; ReLU (ELU+ReLU
// collapses to ReLU) -> H1.
// ---------------------------------------------------------------------------
__global__ __launch_bounds__(256) void attn1_kernel(const int* __restrict__ nbr,
                                                    const int* __restrict__ cnt,
                                                    const float* __restrict__ H,
                                                    const float* __restrict__ fs,
                                                    const float* __restrict__ fd,
                                                    float* __restrict__ H1) {
  __shared__ float att[2][MAXD];
  __shared__ int jidx[MAXD];
  int i = blockIdx.x;
  int t = threadIdx.x;
  int deg = cnt[i];
  if (t < MAXD && t < deg) {
    int j = nbr[(size_t)i * MAXD + t];
    jidx[t] = j;
    att[0][t] = lrelu(fs[i] + fd[j]);
    att[1][t] = lrelu(fs[NN + i] + fd[NN + j]);
  }
  __syncthreads();
  int wave = t >> 6, lane = t & 63;
  if (wave < 2) {
    int k = wave;
    float e0 = (lane < deg) ? att[k][lane] : -INFINITY;
    float e1 = (lane + 64 < deg) ? att[k][lane + 64] : -INFINITY;
    float m = fmaxf(e0, e1);
#pragma unroll
    for (int off = 32; off > 0; off >>= 1) m = fmaxf(m, __shfl_xor(m, off));
    float p0 = (lane < deg) ? expf(e0 - m) : 0.f;
    float p1 = (lane + 64 < deg) ? expf(e1 - m) : 0.f;
    float s = p0 + p1;
#pragma unroll
    for (int off = 32; off > 0; off >>= 1) s += __shfl_xor(s, off);
    float inv = 1.f / s;   // s > 0 guaranteed by self-loop
    if (lane < deg) att[k][lane] = p0 * inv;
    if (lane + 64 < deg) att[k][lane + 64] = p1 * inv;
  }
  __syncthreads();
  int k = t >> 7;
  float acc = 0.f;
  for (int q = 0; q < deg; ++q) acc += att[k][q] * H[(size_t)jidx[q] * HC + t];
  H1[(size_t)i * HC + t] = fmaxf(acc, 0.f);  // relu(elu(z)) == relu(z)
}

// ---------------------------------------------------------------------------
// H2[8192][16] = H1[8192][256] @ W2[256][16], fused f2_src/f2_dst reduction.
// 16 rows x 16 cols of threads per block; W2 staged in LDS.
// ---------------------------------------------------------------------------
__global__ __launch_bounds__(256) void gemm2_kernel(const float* __restrict__ H1,
                                                    const float* __restrict__ W2,
                                                    const float* __restrict__ a2s,
                                                    const float* __restrict__ a2d,
                                                    float* __restrict__ H2,
                                                    float* __restrict__ f2s,
                                                    float* __restrict__ f2d) {
  __shared__ float Ws[HC * COUT];
  int tid = threadIdx.x;
#pragma unroll
  for (int r = 0; r < 16; ++r) Ws[r * 256 + tid] = W2[r * 256 + tid];
  __syncthreads();
  int rg = tid >> 4, c = tid & 15;
  int n = blockIdx.x * 16 + rg;
  const float* h1r = H1 + (size_t)n * HC;
  float acc = 0.f;
#pragma unroll 8
  for (int kk = 0; kk < HC; ++kk) acc += h1r[kk] * Ws[kk * COUT + c];
  H2[(size_t)n * COUT + c] = acc;
  float s = acc * a2s[c];
  float d = acc * a2d[c];
#pragma unroll
  for (int off = 8; off > 0; off >>= 1) {
    s += __shfl_xor(s, off, 16);
    d += __shfl_xor(d, off, 16);
  }
  if (c == 0) { f2s[n] = s; f2d[n] = d; }
}

// ---------------------------------------------------------------------------
// Layer-2 sparse attention; K=1 head so mean == identity. One wave per row.
// ---------------------------------------------------------------------------
__global__ __launch_bounds__(64) void attn2_kernel(const int* __restrict__ nbr,
                                                   const int* __restrict__ cnt,
                                                   const float* __restrict__ H2,
                                                   const float* __restrict__ fs,
                                                   const float* __restrict__ fd,
                                                   float* __restrict__ out) {
  __shared__ float att[MAXD];
  __shared__ int jj[MAXD];
  int i = blockIdx.x;
  int lane = threadIdx.x;
  int deg = cnt[i];
  float fsi = fs[i];
  int j0 = (lane < deg) ? nbr[(size_t)i * MAXD + lane] : 0;
  int j1 = (lane + 64 < deg) ? nbr[(size_t)i * MAXD + lane + 64] : 0;
  float e0 = (lane < deg) ? lrelu(fsi + fd[j0]) : -INFINITY;
  float e1 = (lane + 64 < deg) ? lrelu(fsi + fd[j1]) : -INFINITY;
  float m = fmaxf(e0, e1);
#pragma unroll
  for (int off = 32; off > 0; off >>= 1) m = fmaxf(m, __shfl_xor(m, off));
  float p0 = (lane < deg) ? expf(e0 - m) : 0.f;
  float p1 = (lane + 64 < deg) ? expf(e1 - m) : 0.f;
  float s = p0 + p1;
#pragma unroll
  for (int off = 32; off > 0; off >>= 1) s += __shfl_xor(s, off);
  float inv = 1.f / s;
  att[lane] = p0 * inv;
  att[lane + 64] = p1 * inv;
  jj[lane] = j0;
  jj[lane + 64] = j1;
  __syncthreads();
  if (lane < COUT) {
    float acc = 0.f;
    for (int q = 0; q < deg; ++q) acc += att[q] * H2[(size_t)jj[q] * COUT + lane];
    out[(size_t)i * COUT + lane] = acc;
  }
}

// ---------------------------------------------------------------------------
extern "C" void kernel_launch(void* const* d_in, const int* in_sizes, int n_in,
                              void* d_out, int out_size, void* d_ws, size_t ws_size,
                              hipStream_t stream) {
  const float* x   = (const float*)d_in[0];
  const void*  adj = d_in[1];
  const float* W1  = (const float*)d_in[2];
  const float* a1s = (const float*)d_in[3];
  const float* a1d = (const float*)d_in[4];
  const float* W2  = (const float*)d_in[5];
  const float* a2s = (const float*)d_in[6];
  const float* a2d = (const float*)d_in[7];
  float* out = (float*)d_out;

  char* ws = (char*)d_ws;
  size_t off = 0;
  auto alloc = [&](size_t bytes) -> void* {
    void* p = ws + off;
    off = (off + bytes + 255) & ~(size_t)255;
    return p;
  };
  int*   flag = (int*)  alloc(4);
  int*   nbr  = (int*)  alloc((size_t)NN * MAXD * 4);
  int*   cnt  = (int*)  alloc((size_t)NN * 4);
  float* Wc   = (float*)alloc((size_t)FIN * HC * 4);
  float* H    = (float*)alloc((size_t)NN * HC * 4);
  float* fs   = (float*)alloc((size_t)2 * NN * 4);
  float* fd   = (float*)alloc((size_t)2 * NN * 4);
  float* H1   = (float*)alloc((size_t)NN * HC * 4);
  float* H2   = (float*)alloc((size_t)NN * COUT * 4);
  float* f2s  = (float*)alloc((size_t)NN * 4);
  float* f2d  = (float*)alloc((size_t)NN * 4);

  hipLaunchKernelGGL(detect_kernel, dim3(1), dim3(64), 0, stream, (const int*)adj, flag);
  hipLaunchKernelGGL(build_csr, dim3(NN), dim3(256), 0, stream, adj, flag, nbr, cnt);
  hipLaunchKernelGGL(repack_w1, dim3(512), dim3(256), 0, stream, W1, Wc);
  hipLaunchKernelGGL(gemm1_kernel, dim3(128, 4), dim3(256), 0, stream, x, Wc, H);
  hipLaunchKernelGGL(f1_kernel, dim3(NN / 4), dim3(256), 0, stream, H, a1s, a1d, fs, fd);
  hipLaunchKernelGGL(attn1_kernel, dim3(NN), dim3(256), 0, stream, nbr, cnt, H, fs, fd, H1);
  hipLaunchKernelGGL(gemm2_kernel, dim3(NN / 16), dim3(256), 0, stream, H1, W2, a2s, a2d, H2, f2s, f2d);
  hipLaunchKernelGGL(attn2_kernel, dim3(NN), dim3(64), 0, stream, nbr, cnt, H2, f2s, f2d, out);
}

// Round 2
// 459.449 us; speedup vs baseline: 1.0029x; 1.0029x over previous
//
#include <hip/hip_runtime.h>
#include <hip/hip_bf16.h>
#include <math.h>

constexpr int NN   = 8192;   // nodes
constexpr int FIN  = 512;    // input features
constexpr int HC   = 256;    // concat hidden = K(2) * H(128)
constexpr int COUT = 16;     // classes
constexpr int MAXD = 128;    // neighbor cap (avg deg ~33, max ~60)

typedef __attribute__((ext_vector_type(8))) short bf16x8;
typedef __attribute__((ext_vector_type(4))) float f32x4;

__device__ __forceinline__ float lrelu(float x) { return x > 0.f ? x : 0.2f * x; }

__device__ __forceinline__ unsigned short f2bf(float f) {  // RNE truncate f32->bf16
  unsigned u = __float_as_uint(f);
  return (unsigned short)((u + 0x7fffu + ((u >> 16) & 1u)) >> 16);
}
__device__ __forceinline__ float bf2f(unsigned short h) {
  unsigned u = ((unsigned)h) << 16;
  return __uint_as_float(u);
}

// ---------------------------------------------------------------------------
// Detect adjacency element width (diagonal is all-ones due to self-loops).
// ---------------------------------------------------------------------------
__global__ __launch_bounds__(64) void detect_kernel(const int* __restrict__ adj32,
                                                    int* __restrict__ flag) {
  int lane = threadIdx.x;
  size_t idx = (size_t)(lane * 32) * (size_t)(NN + 1);
  int v = adj32[idx];
  bool four = (v == 1) || (v == 0x3f800000);
  unsigned long long b = __ballot(four);
  if (lane == 0) flag[0] = (b == ~0ull) ? 1 : 0;
}

// ---------------------------------------------------------------------------
// Dense adjacency row scan -> neighbor lists (unordered). One block per row.
// ---------------------------------------------------------------------------
__global__ __launch_bounds__(256) void build_csr(const void* __restrict__ adj,
                                                 const int* __restrict__ flag,
                                                 int* __restrict__ nbr,
                                                 int* __restrict__ cnt) {
  __shared__ int scnt;
  int i = blockIdx.x;
  if (threadIdx.x == 0) scnt = 0;
  __syncthreads();
  int* row_out = nbr + (size_t)i * MAXD;
  if (flag[0]) {  // 4-byte elements
    const int4* row = reinterpret_cast<const int4*>((const int*)adj + (size_t)i * NN);
#pragma unroll
    for (int rep = 0; rep < 8; ++rep) {
      int vi = rep * 256 + threadIdx.x;
      int4 v = row[vi];
      int base = vi * 4;
      if (v.x) { int p = atomicAdd(&scnt, 1); if (p < MAXD) row_out[p] = base; }
      if (v.y) { int p = atomicAdd(&scnt, 1); if (p < MAXD) row_out[p] = base + 1; }
      if (v.z) { int p = atomicAdd(&scnt, 1); if (p < MAXD) row_out[p] = base + 2; }
      if (v.w) { int p = atomicAdd(&scnt, 1); if (p < MAXD) row_out[p] = base + 3; }
    }
  } else {  // 1-byte elements
    const uint4* row = reinterpret_cast<const uint4*>((const unsigned char*)adj + (size_t)i * NN);
#pragma unroll
    for (int rep = 0; rep < 2; ++rep) {
      int vi = rep * 256 + threadIdx.x;
      uint4 v = row[vi];
      int base = vi * 16;
      unsigned w[4] = {v.x, v.y, v.z, v.w};
#pragma unroll
      for (int q = 0; q < 4; ++q)
#pragma unroll
        for (int b = 0; b < 4; ++b)
          if ((w[q] >> (8 * b)) & 0xffu) {
            int p = atomicAdd(&scnt, 1);
            if (p < MAXD) row_out[p] = base + q * 4 + b;
          }
    }
  }
  __syncthreads();
  if (threadIdx.x == 0) cnt[i] = scnt < MAXD ? scnt : MAXD;
}

// ---------------------------------------------------------------------------
// x [8192][512] fp32 -> split bf16 pair Xh/Xl (x ~= hi + lo, lo |x|*2^-9).
// ---------------------------------------------------------------------------
__global__ __launch_bounds__(256) void convert_x(const float* __restrict__ x,
                                                 unsigned short* __restrict__ Xh,
                                                 unsigned short* __restrict__ Xl) {
  int t = blockIdx.x * 256 + threadIdx.x;     // handles 4 floats
  float4 v = *reinterpret_cast<const float4*>(x + (size_t)t * 4);
  ushort4 hi, lo;
  hi.x = f2bf(v.x); lo.x = f2bf(v.x - bf2f(hi.x));
  hi.y = f2bf(v.y); lo.y = f2bf(v.y - bf2f(hi.y));
  hi.z = f2bf(v.z); lo.z = f2bf(v.z - bf2f(hi.z));
  hi.w = f2bf(v.w); lo.w = f2bf(v.w - bf2f(hi.w));
  *reinterpret_cast<ushort4*>(Xh + (size_t)t * 4) = hi;
  *reinterpret_cast<ushort4*>(Xl + (size_t)t * 4) = lo;
}

// ---------------------------------------------------------------------------
// W1 [K=2][F=512][H=128] -> transposed-concat split-bf16 Wt[n=k*128+h][f],
// so the MFMA B-fragment (8 consecutive k's of one column) is a b128 load.
// ---------------------------------------------------------------------------
__global__ __launch_bounds__(256) void convert_w(const float* __restrict__ W1,
                                                 unsigned short* __restrict__ Wth,
                                                 unsigned short* __restrict__ Wtl) {
  int idx = blockIdx.x * 256 + threadIdx.x;   // n*512 + kk, 131072 total
  int n = idx >> 9, kk = idx & 511;
  int k = n >> 7, h = n & 127;
  float v = W1[k * 65536 + kk * 128 + h];
  unsigned short hi = f2bf(v);
  Wth[idx] = hi;
  Wtl[idx] = f2bf(v - bf2f(hi));
}

// ---------------------------------------------------------------------------
// H[8192][256] = X[8192][512] @ Wc[512][256] via split-bf16 MFMA (3 products:
// Ah*Bh + Ah*Bl + Al*Bh; dropped Al*Bl ~ 2^-18 rel). fp32-grade accuracy.
// Wave tile 32x64 (2x4 fragments of 16x16x32). Block = 4 waves = 128 rows.
// A/B fragments loaded straight from global (B is 512KB -> L2-resident).
// ---------------------------------------------------------------------------
__global__ __launch_bounds__(256) void gemm1m(const unsigned short* __restrict__ Xh,
                                              const unsigned short* __restrict__ Xl,
                                              const unsigned short* __restrict__ Bh,
                                              const unsigned short* __restrict__ Bl,
                                              float* __restrict__ Hout) {
  int wave = threadIdx.x >> 6, lane = threadIdx.x & 63;
  int rowBase = blockIdx.x * 128 + wave * 32;
  int colBase = blockIdx.y * 64;
  int frow = lane & 15;            // A-row / B-col within fragment
  int kchunk = (lane >> 4) * 8;    // k sub-chunk within the 32-wide step
  f32x4 acc[2][4] = {};
  for (int k0 = 0; k0 < FIN; k0 += 32) {
    bf16x8 ah[2], al[2], bh[4], bl[4];
#pragma unroll
    for (int r = 0; r < 2; ++r) {
      size_t off = (size_t)(rowBase + r * 16 + frow) * FIN + k0 + kchunk;
      ah[r] = *reinterpret_cast<const bf16x8*>(Xh + off);
      al[r] = *reinterpret_cast<const bf16x8*>(Xl + off);
    }
#pragma unroll
    for (int c = 0; c < 4; ++c) {
      size_t off = (size_t)(colBase + c * 16 + frow) * FIN + k0 + kchunk;
      bh[c] = *reinterpret_cast<const bf16x8*>(Bh + off);
      bl[c] = *reinterpret_cast<const bf16x8*>(Bl + off);
    }
#pragma unroll
    for (int r = 0; r < 2; ++r)
#pragma unroll
      for (int c = 0; c < 4; ++c) {
        acc[r][c] = __builtin_amdgcn_mfma_f32_16x16x32_bf16(ah[r], bh[c], acc[r][c], 0, 0, 0);
        acc[r][c] = __builtin_amdgcn_mfma_f32_16x16x32_bf16(ah[r], bl[c], acc[r][c], 0, 0, 0);
        acc[r][c] = __builtin_amdgcn_mfma_f32_16x16x32_bf16(al[r], bh[c], acc[r][c], 0, 0, 0);
      }
  }
  // D fragment: col = lane&15, row = (lane>>4)*4 + reg   [m89-verified]
  int dcol = lane & 15, drow4 = (lane >> 4) * 4;
#pragma unroll
  for (int r = 0; r < 2; ++r)
#pragma unroll
    for (int c = 0; c < 4; ++c)
#pragma unroll
      for (int q = 0; q < 4; ++q)
        Hout[(size_t)(rowBase + r * 16 + drow4 + q) * HC + colBase + c * 16 + dcol] =
            acc[r][c][q];
}

// ---------------------------------------------------------------------------
// f_src[k][n], f_dst[k][n] dots. One wave per node.
// ---------------------------------------------------------------------------
__global__ __launch_bounds__(256) void f1_kernel(const float* __restrict__ H,
                                                 const float* __restrict__ a_src,
                                                 const float* __restrict__ a_dst,
                                                 float* __restrict__ fs,
                                                 float* __restrict__ fd) {
  int wave = threadIdx.x >> 6, lane = threadIdx.x & 63;
  int n = blockIdx.x * 4 + wave;
  const float* hr = H + (size_t)n * HC;
  float h0 = hr[lane], h1 = hr[lane + 64], h2 = hr[lane + 128], h3 = hr[lane + 192];
  float s0 = h0 * a_src[lane] + h1 * a_src[lane + 64];
  float s1 = h2 * a_src[lane + 128] + h3 * a_src[lane + 192];
  float d0 = h0 * a_dst[lane] + h1 * a_dst[lane + 64];
  float d1 = h2 * a_dst[lane + 128] + h3 * a_dst[lane + 192];
#pragma unroll
  for (int off = 32; off > 0; off >>= 1) {
    s0 += __shfl_xor(s0, off);
    s1 += __shfl_xor(s1, off);
    d0 += __shfl_xor(d0, off);
    d1 += __shfl_xor(d1, off);
  }
  if (lane == 0) {
    fs[n] = s0; fs[NN + n] = s1;
    fd[n] = d0; fd[NN + n] = d1;
  }
}

// ---------------------------------------------------------------------------
// Layer-1 sparse attention. One block (256 thr) per row i.
// PV loop unrolled x4 so 4 gather loads are in flight per thread.
// ---------------------------------------------------------------------------
__global__ __launch_bounds__(256) void attn1_kernel(const int* __restrict__ nbr,
                                                    const int* __restrict__ cnt,
                                                    const float* __restrict__ H,
                                                    const float* __restrict__ fs,
                                                    const float* __restrict__ fd,
                                                    float* __restrict__ H1) {
  __shared__ float att[2][MAXD];
  __shared__ int jidx[MAXD];
  int i = blockIdx.x;
  int t = threadIdx.x;
  int deg = cnt[i];
  if (t < MAXD && t < deg) {
    int j = nbr[(size_t)i * MAXD + t];
    jidx[t] = j;
    att[0][t] = lrelu(fs[i] + fd[j]);
    att[1][t] = lrelu(fs[NN + i] + fd[NN + j]);
  }
  __syncthreads();
  int wave = t >> 6, lane = t & 63;
  if (wave < 2) {
    int k = wave;
    float e0 = (lane < deg) ? att[k][lane] : -INFINITY;
    float e1 = (lane + 64 < deg) ? att[k][lane + 64] : -INFINITY;
    float m = fmaxf(e0, e1);
#pragma unroll
    for (int off = 32; off > 0; off >>= 1) m = fmaxf(m, __shfl_xor(m, off));
    float p0 = (lane < deg) ? expf(e0 - m) : 0.f;
    float p1 = (lane + 64 < deg) ? expf(e1 - m) : 0.f;
    float s = p0 + p1;
#pragma unroll
    for (int off = 32; off > 0; off >>= 1) s += __shfl_xor(s, off);
    float inv = 1.f / s;   // s > 0 guaranteed by self-loop
    if (lane < deg) att[k][lane] = p0 * inv;
    if (lane + 64 < deg) att[k][lane + 64] = p1 * inv;
  }
  __syncthreads();
  int k = t >> 7;
  float acc = 0.f;
  int q = 0;
  for (; q + 4 <= deg; q += 4) {
    float a0 = att[k][q], a1 = att[k][q + 1], a2 = att[k][q + 2], a3 = att[k][q + 3];
    int j0 = jidx[q], j1 = jidx[q + 1], j2 = jidx[q + 2], j3 = jidx[q + 3];
    float g0 = H[(size_t)j0 * HC + t];
    float g1 = H[(size_t)j1 * HC + t];
    float g2 = H[(size_t)j2 * HC + t];
    float g3 = H[(size_t)j3 * HC + t];
    acc += a0 * g0 + a1 * g1 + a2 * g2 + a3 * g3;
  }
  for (; q < deg; ++q) acc += att[k][q] * H[(size_t)jidx[q] * HC + t];
  H1[(size_t)i * HC + t] = fmaxf(acc, 0.f);  // relu(elu(z)) == relu(z)
}

// ---------------------------------------------------------------------------
// H2[8192][16] = H1[8192][256] @ W2[256][16], fused f2_src/f2_dst reduction.
// ---------------------------------------------------------------------------
__global__ __launch_bounds__(256) void gemm2_kernel(const float* __restrict__ H1,
                                                    const float* __restrict__ W2,
                                                    const float* __restrict__ a2s,
                                                    const float* __restrict__ a2d,
                                                    float* __restrict__ H2,
                                                    float* __restrict__ f2s,
                                                    float* __restrict__ f2d) {
  __shared__ float Ws[HC * COUT];
  int tid = threadIdx.x;
#pragma unroll
  for (int r = 0; r < 16; ++r) Ws[r * 256 + tid] = W2[r * 256 + tid];
  __syncthreads();
  int rg = tid >> 4, c = tid & 15;
  int n = blockIdx.x * 16 + rg;
  const float* h1r = H1 + (size_t)n * HC;
  float acc = 0.f;
#pragma unroll 8
  for (int kk = 0; kk < HC; ++kk) acc += h1r[kk] * Ws[kk * COUT + c];
  H2[(size_t)n * COUT + c] = acc;
  float s = acc * a2s[c];
  float d = acc * a2d[c];
#pragma unroll
  for (int off = 8; off > 0; off >>= 1) {
    s += __shfl_xor(s, off, 16);
    d += __shfl_xor(d, off, 16);
  }
  if (c == 0) { f2s[n] = s; f2d[n] = d; }
}

// ---------------------------------------------------------------------------
// Layer-2 sparse attention; K=1 head so mean == identity. One wave per row.
// ---------------------------------------------------------------------------
__global__ __launch_bounds__(64) void attn2_kernel(const int* __restrict__ nbr,
                                                   const int* __restrict__ cnt,
                                                   const float* __restrict__ H2,
                                                   const float* __restrict__ fs,
                                                   const float* __restrict__ fd,
                                                   float* __restrict__ out) {
  __shared__ float att[MAXD];
  __shared__ int jj[MAXD];
  int i = blockIdx.x;
  int lane = threadIdx.x;
  int deg = cnt[i];
  float fsi = fs[i];
  int j0 = (lane < deg) ? nbr[(size_t)i * MAXD + lane] : 0;
  int j1 = (lane + 64 < deg) ? nbr[(size_t)i * MAXD + lane + 64] : 0;
  float e0 = (lane < deg) ? lrelu(fsi + fd[j0]) : -INFINITY;
  float e1 = (lane + 64 < deg) ? lrelu(fsi + fd[j1]) : -INFINITY;
  float m = fmaxf(e0, e1);
#pragma unroll
  for (int off = 32; off > 0; off >>= 1) m = fmaxf(m, __shfl_xor(m, off));
  float p0 = (lane < deg) ? expf(e0 - m) : 0.f;
  float p1 = (lane + 64 < deg) ? expf(e1 - m) : 0.f;
  float s = p0 + p1;
#pragma unroll
  for (int off = 32; off > 0; off >>= 1) s += __shfl_xor(s, off);
  float inv = 1.f / s;
  att[lane] = p0 * inv;
  att[lane + 64] = p1 * inv;
  jj[lane] = j0;
  jj[lane + 64] = j1;
  __syncthreads();
  if (lane < COUT) {
    float acc = 0.f;
    for (int q = 0; q < deg; ++q) acc += att[q] * H2[(size_t)jj[q] * COUT + lane];
    out[(size_t)i * COUT + lane] = acc;
  }
}

// ---------------------------------------------------------------------------
extern "C" void kernel_launch(void* const* d_in, const int* in_sizes, int n_in,
                              void* d_out, int out_size, void* d_ws, size_t ws_size,
                              hipStream_t stream) {
  const float* x   = (const float*)d_in[0];
  const void*  adj = d_in[1];
  const float* W1  = (const float*)d_in[2];
  const float* a1s = (const float*)d_in[3];
  const float* a1d = (const float*)d_in[4];
  const float* W2  = (const float*)d_in[5];
  const float* a2s = (const float*)d_in[6];
  const float* a2d = (const float*)d_in[7];
  float* out = (float*)d_out;

  char* ws = (char*)d_ws;
  size_t off = 0;
  auto alloc = [&](size_t bytes) -> void* {
    void* p = ws + off;
    off = (off + bytes + 255) & ~(size_t)255;
    return p;
  };
  int*            flag = (int*)           alloc(4);
  int*            nbr  = (int*)           alloc((size_t)NN * MAXD * 4);
  int*            cnt  = (int*)           alloc((size_t)NN * 4);
  unsigned short* Xh   = (unsigned short*)alloc((size_t)NN * FIN * 2);
  unsigned short* Xl   = (unsigned short*)alloc((size_t)NN * FIN * 2);
  unsigned short* Wth  = (unsigned short*)alloc((size_t)HC * FIN * 2);
  unsigned short* Wtl  = (unsigned short*)alloc((size_t)HC * FIN * 2);
  float*          H    = (float*)         alloc((size_t)NN * HC * 4);
  float*          fs   = (float*)         alloc((size_t)2 * NN * 4);
  float*          fd   = (float*)         alloc((size_t)2 * NN * 4);
  float*          H1   = (float*)         alloc((size_t)NN * HC * 4);
  float*          H2   = (float*)         alloc((size_t)NN * COUT * 4);
  float*          f2s  = (float*)         alloc((size_t)NN * 4);
  float*          f2d  = (float*)         alloc((size_t)NN * 4);

  hipLaunchKernelGGL(detect_kernel, dim3(1), dim3(64), 0, stream, (const int*)adj, flag);
  hipLaunchKernelGGL(build_csr, dim3(NN), dim3(256), 0, stream, adj, flag, nbr, cnt);
  hipLaunchKernelGGL(convert_x, dim3(NN * FIN / 1024), dim3(256), 0, stream, x, Xh, Xl);
  hipLaunchKernelGGL(convert_w, dim3(HC * FIN / 256), dim3(256), 0, stream, W1, Wth, Wtl);
  hipLaunchKernelGGL(gemm1m, dim3(NN / 128, HC / 64), dim3(256), 0, stream, Xh, Xl, Wth, Wtl, H);
  hipLaunchKernelGGL(f1_kernel, dim3(NN / 4), dim3(256), 0, stream, H, a1s, a1d, fs, fd);
  hipLaunchKernelGGL(attn1_kernel, dim3(NN), dim3(256), 0, stream, nbr, cnt, H, fs, fd, H1);
  hipLaunchKernelGGL(gemm2_kernel, dim3(NN / 16), dim3(256), 0, stream, H1, W2, a2s, a2d, H2, f2s, f2d);
  hipLaunchKernelGGL(attn2_kernel, dim3(NN), dim3(64), 0, stream, nbr, cnt, H2, f2s, f2d, out);
}

// Round 4
// 456.844 us; speedup vs baseline: 1.0087x; 1.0057x over previous
//
#include <hip/hip_runtime.h>
#include <hip/hip_bf16.h>
#include <math.h>

constexpr int NN   = 8192;   // nodes
constexpr int FIN  = 512;    // input features
constexpr int HC   = 256;    // concat hidden = K(2) * H(128)
constexpr int COUT = 16;     // classes
constexpr int MAXD = 128;    // neighbor cap (avg deg ~33, max ~60)

typedef __attribute__((ext_vector_type(8))) short bf16x8;
typedef __attribute__((ext_vector_type(4))) float f32x4;

__device__ __forceinline__ float lrelu(float x) { return x > 0.f ? x : 0.2f * x; }

__device__ __forceinline__ unsigned short f2bf(float f) {  // RNE f32->bf16
  unsigned u = __float_as_uint(f);
  return (unsigned short)((u + 0x7fffu + ((u >> 16) & 1u)) >> 16);
}
__device__ __forceinline__ float bf2f(unsigned short h) {
  unsigned u = ((unsigned)h) << 16;
  return __uint_as_float(u);
}

// ---------------------------------------------------------------------------
// prep: convert_x (blocks 0..4095), convert_w (4096..4607), zero fs/fd
// (4608..4735). One launch instead of three.
// ---------------------------------------------------------------------------
__global__ __launch_bounds__(256) void prep_kernel(const float* __restrict__ x,
                                                   const float* __restrict__ W1,
                                                   unsigned short* __restrict__ Xh,
                                                   unsigned short* __restrict__ Xl,
                                                   unsigned short* __restrict__ Wth,
                                                   unsigned short* __restrict__ Wtl,
                                                   float* __restrict__ fs,
                                                   float* __restrict__ fd) {
  int b = blockIdx.x;
  if (b < 4096) {  // x [8192][512] -> split bf16 (4 floats / thread)
    int t = b * 256 + threadIdx.x;
    float4 v = *reinterpret_cast<const float4*>(x + (size_t)t * 4);
    ushort4 hi, lo;
    hi.x = f2bf(v.x); lo.x = f2bf(v.x - bf2f(hi.x));
    hi.y = f2bf(v.y); lo.y = f2bf(v.y - bf2f(hi.y));
    hi.z = f2bf(v.z); lo.z = f2bf(v.z - bf2f(hi.z));
    hi.w = f2bf(v.w); lo.w = f2bf(v.w - bf2f(hi.w));
    *reinterpret_cast<ushort4*>(Xh + (size_t)t * 4) = hi;
    *reinterpret_cast<ushort4*>(Xl + (size_t)t * 4) = lo;
  } else if (b < 4608) {  // W1 [2][512][128] -> transposed-concat split bf16 [n][f]
    int idx = (b - 4096) * 256 + threadIdx.x;  // n*512 + kk
    int n = idx >> 9, kk = idx & 511;
    int k = n >> 7, h = n & 127;
    float v = W1[k * 65536 + kk * 128 + h];
    unsigned short hi = f2bf(v);
    Wth[idx] = hi;
    Wtl[idx] = f2bf(v - bf2f(hi));
  } else {  // zero fs/fd (2*NN floats each) for gemm1m's atomic f-epilogue
    int z = (b - 4608) * 256 + threadIdx.x;  // 0..32767
    if (z < 2 * NN) fs[z] = 0.f;
    else fd[z - 2 * NN] = 0.f;
  }
}

// ---------------------------------------------------------------------------
// Dense adjacency row scan -> neighbor lists. One block per row.
// Element width detected inline per block (diagonal all-ones from self-loops):
// 64 int32 probes at diag positions (rows < 2048 keep int32 view in-bounds
// even for a uint8 buffer) -> all 1/0x3f800000 => 4-byte elems.
// ---------------------------------------------------------------------------
__global__ __launch_bounds__(256) void build_csr(const void* __restrict__ adj,
                                                 int* __restrict__ nbr,
                                                 int* __restrict__ cnt) {
  __shared__ int scnt;
  __shared__ int sflag;
  int i = blockIdx.x;
  int t = threadIdx.x;
  if (t == 0) scnt = 0;
  if (t < 64) {
    size_t idx = (size_t)(t * 32) * (size_t)(NN + 1);
    int v = ((const int*)adj)[idx];
    bool four = (v == 1) || (v == 0x3f800000);
    unsigned long long b = __ballot(four);
    if (t == 0) sflag = (b == ~0ull) ? 1 : 0;
  }
  __syncthreads();
  int* row_out = nbr + (size_t)i * MAXD;
  if (sflag) {  // 4-byte elements (int32 or fp32: nonzero bits == edge)
    const int4* row = reinterpret_cast<const int4*>((const int*)adj + (size_t)i * NN);
#pragma unroll
    for (int rep = 0; rep < 8; ++rep) {
      int vi = rep * 256 + t;
      int4 v = row[vi];
      int base = vi * 4;
      if (v.x) { int p = atomicAdd(&scnt, 1); if (p < MAXD) row_out[p] = base; }
      if (v.y) { int p = atomicAdd(&scnt, 1); if (p < MAXD) row_out[p] = base + 1; }
      if (v.z) { int p = atomicAdd(&scnt, 1); if (p < MAXD) row_out[p] = base + 2; }
      if (v.w) { int p = atomicAdd(&scnt, 1); if (p < MAXD) row_out[p] = base + 3; }
    }
  } else {  // 1-byte elements
    const uint4* row = reinterpret_cast<const uint4*>((const unsigned char*)adj + (size_t)i * NN);
#pragma unroll
    for (int rep = 0; rep < 2; ++rep) {
      int vi = rep * 256 + t;
      uint4 v = row[vi];
      int base = vi * 16;
      unsigned w[4] = {v.x, v.y, v.z, v.w};
#pragma unroll
      for (int q = 0; q < 4; ++q)
#pragma unroll
        for (int bb = 0; bb < 4; ++bb)
          if ((w[q] >> (8 * bb)) & 0xffu) {
            int p = atomicAdd(&scnt, 1);
            if (p < MAXD) row_out[p] = base + q * 4 + bb;
          }
    }
  }
  __syncthreads();
  if (t == 0) cnt[i] = scnt < MAXD ? scnt : MAXD;
}

// ---------------------------------------------------------------------------
// H[8192][256] = X @ Wc via split-bf16 MFMA (Ah*Bh + Ah*Bl + Al*Bh).
// Wave tile 32x64; block 128 rows x 64 cols. Fused f-epilogue: the wave
// already holds H fragments -> dot with a1_src/a1_dst, 16-lane shfl reduce,
// one atomicAdd per row per block into fs/fd (zeroed by prep).
// ---------------------------------------------------------------------------
__global__ __launch_bounds__(256) void gemm1m(const unsigned short* __restrict__ Xh,
                                              const unsigned short* __restrict__ Xl,
                                              const unsigned short* __restrict__ Bh,
                                              const unsigned short* __restrict__ Bl,
                                              const float* __restrict__ a1s,
                                              const float* __restrict__ a1d,
                                              float* __restrict__ Hout,
                                              float* __restrict__ fs,
                                              float* __restrict__ fd) {
  int wave = threadIdx.x >> 6, lane = threadIdx.x & 63;
  int rowBase = blockIdx.x * 128 + wave * 32;
  int colBase = blockIdx.y * 64;
  int frow = lane & 15;            // A-row / B-col within fragment
  int kchunk = (lane >> 4) * 8;    // k sub-chunk within the 32-wide step
  f32x4 acc[2][4] = {};
  for (int k0 = 0; k0 < FIN; k0 += 32) {
    bf16x8 ah[2], al[2], bh[4], bl[4];
#pragma unroll
    for (int r = 0; r < 2; ++r) {
      size_t off = (size_t)(rowBase + r * 16 + frow) * FIN + k0 + kchunk;
      ah[r] = *reinterpret_cast<const bf16x8*>(Xh + off);
      al[r] = *reinterpret_cast<const bf16x8*>(Xl + off);
    }
#pragma unroll
    for (int c = 0; c < 4; ++c) {
      size_t off = (size_t)(colBase + c * 16 + frow) * FIN + k0 + kchunk;
      bh[c] = *reinterpret_cast<const bf16x8*>(Bh + off);
      bl[c] = *reinterpret_cast<const bf16x8*>(Bl + off);
    }
#pragma unroll
    for (int r = 0; r < 2; ++r)
#pragma unroll
      for (int c = 0; c < 4; ++c) {
        acc[r][c] = __builtin_amdgcn_mfma_f32_16x16x32_bf16(ah[r], bh[c], acc[r][c], 0, 0, 0);
        acc[r][c] = __builtin_amdgcn_mfma_f32_16x16x32_bf16(ah[r], bl[c], acc[r][c], 0, 0, 0);
        acc[r][c] = __builtin_amdgcn_mfma_f32_16x16x32_bf16(al[r], bh[c], acc[r][c], 0, 0, 0);
      }
  }
  // D fragment: col = lane&15, row = (lane>>4)*4 + reg   [m89-verified]
  int dcol = lane & 15, drow4 = (lane >> 4) * 4;
#pragma unroll
  for (int r = 0; r < 2; ++r)
#pragma unroll
    for (int c = 0; c < 4; ++c)
#pragma unroll
      for (int q = 0; q < 4; ++q)
        Hout[(size_t)(rowBase + r * 16 + drow4 + q) * HC + colBase + c * 16 + dcol] =
            acc[r][c][q];
  // fused f_src/f_dst partial reduction (cols colBase..colBase+63, one head)
  int khead = colBase >> 7;
  float as[4], ad[4];
#pragma unroll
  for (int c = 0; c < 4; ++c) {
    as[c] = a1s[colBase + c * 16 + dcol];
    ad[c] = a1d[colBase + c * 16 + dcol];
  }
#pragma unroll
  for (int r = 0; r < 2; ++r)
#pragma unroll
    for (int q = 0; q < 4; ++q) {
      float s = 0.f, d = 0.f;
#pragma unroll
      for (int c = 0; c < 4; ++c) {
        float v = acc[r][c][q];
        s += v * as[c];
        d += v * ad[c];
      }
#pragma unroll
      for (int off = 8; off > 0; off >>= 1) {
        s += __shfl_xor(s, off, 16);
        d += __shfl_xor(d, off, 16);
      }
      if ((lane & 15) == 0) {
        int row = rowBase + r * 16 + drow4 + q;
        atomicAdd(fs + khead * NN + row, s);
        atomicAdd(fd + khead * NN + row, d);
      }
    }
}

// ---------------------------------------------------------------------------
// Layer-1 sparse attention. One block (256 thr) per row i. PV unrolled x4.
// ---------------------------------------------------------------------------
__global__ __launch_bounds__(256) void attn1_kernel(const int* __restrict__ nbr,
                                                    const int* __restrict__ cnt,
                                                    const float* __restrict__ H,
                                                    const float* __restrict__ fs,
                                                    const float* __restrict__ fd,
                                                    float* __restrict__ H1) {
  __shared__ float att[2][MAXD];
  __shared__ int jidx[MAXD];
  int i = blockIdx.x;
  int t = threadIdx.x;
  int deg = cnt[i];
  if (t < MAXD && t < deg) {
    int j = nbr[(size_t)i * MAXD + t];
    jidx[t] = j;
    att[0][t] = lrelu(fs[i] + fd[j]);
    att[1][t] = lrelu(fs[NN + i] + fd[NN + j]);
  }
  __syncthreads();
  int wave = t >> 6, lane = t & 63;
  if (wave < 2) {
    int k = wave;
    float e0 = (lane < deg) ? att[k][lane] : -INFINITY;
    float e1 = (lane + 64 < deg) ? att[k][lane + 64] : -INFINITY;
    float m = fmaxf(e0, e1);
#pragma unroll
    for (int off = 32; off > 0; off >>= 1) m = fmaxf(m, __shfl_xor(m, off));
    float p0 = (lane < deg) ? expf(e0 - m) : 0.f;
    float p1 = (lane + 64 < deg) ? expf(e1 - m) : 0.f;
    float s = p0 + p1;
#pragma unroll
    for (int off = 32; off > 0; off >>= 1) s += __shfl_xor(s, off);
    float inv = 1.f / s;   // s > 0 guaranteed by self-loop
    if (lane < deg) att[k][lane] = p0 * inv;
    if (lane + 64 < deg) att[k][lane + 64] = p1 * inv;
  }
  __syncthreads();
  int k = t >> 7;
  float acc = 0.f;
  int q = 0;
  for (; q + 4 <= deg; q += 4) {
    float a0 = att[k][q], a1 = att[k][q + 1], a2 = att[k][q + 2], a3 = att[k][q + 3];
    int j0 = jidx[q], j1 = jidx[q + 1], j2 = jidx[q + 2], j3 = jidx[q + 3];
    float g0 = H[(size_t)j0 * HC + t];
    float g1 = H[(size_t)j1 * HC + t];
    float g2 = H[(size_t)j2 * HC + t];
    float g3 = H[(size_t)j3 * HC + t];
    acc += a0 * g0 + a1 * g1 + a2 * g2 + a3 * g3;
  }
  for (; q < deg; ++q) acc += att[k][q] * H[(size_t)jidx[q] * HC + t];
  H1[(size_t)i * HC + t] = fmaxf(acc, 0.f);  // relu(elu(z)) == relu(z)
}

// ---------------------------------------------------------------------------
// H2[8192][16] = H1[8192][256] @ W2[256][16], fused f2_src/f2_dst reduction.
// ---------------------------------------------------------------------------
__global__ __launch_bounds__(256) void gemm2_kernel(const float* __restrict__ H1,
                                                    const float* __restrict__ W2,
                                                    const float* __restrict__ a2s,
                                                    const float* __restrict__ a2d,
                                                    float* __restrict__ H2,
                                                    float* __restrict__ f2s,
                                                    float* __restrict__ f2d) {
  __shared__ float Ws[HC * COUT];
  int tid = threadIdx.x;
#pragma unroll
  for (int r = 0; r < 16; ++r) Ws[r * 256 + tid] = W2[r * 256 + tid];
  __syncthreads();
  int rg = tid >> 4, c = tid & 15;
  int n = blockIdx.x * 16 + rg;
  const float* h1r = H1 + (size_t)n * HC;
  float acc = 0.f;
#pragma unroll 8
  for (int kk = 0; kk < HC; ++kk) acc += h1r[kk] * Ws[kk * COUT + c];
  H2[(size_t)n * COUT + c] = acc;
  float s = acc * a2s[c];
  float d = acc * a2d[c];
#pragma unroll
  for (int off = 8; off > 0; off >>= 1) {
    s += __shfl_xor(s, off, 16);
    d += __shfl_xor(d, off, 16);
  }
  if (c == 0) { f2s[n] = s; f2d[n] = d; }
}

// ---------------------------------------------------------------------------
// Layer-2 sparse attention; K=1 head so mean == identity. One wave per row.
// ---------------------------------------------------------------------------
__global__ __launch_bounds__(64) void attn2_kernel(const int* __restrict__ nbr,
                                                   const int* __restrict__ cnt,
                                                   const float* __restrict__ H2,
                                                   const float* __restrict__ fs,
                                                   const float* __restrict__ fd,
                                                   float* __restrict__ out) {
  __shared__ float att[MAXD];
  __shared__ int jj[MAXD];
  int i = blockIdx.x;
  int lane = threadIdx.x;
  int deg = cnt[i];
  float fsi = fs[i];
  int j0 = (lane < deg) ? nbr[(size_t)i * MAXD + lane] : 0;
  int j1 = (lane + 64 < deg) ? nbr[(size_t)i * MAXD + lane + 64] : 0;
  float e0 = (lane < deg) ? lrelu(fsi + fd[j0]) : -INFINITY;
  float e1 = (lane + 64 < deg) ? lrelu(fsi + fd[j1]) : -INFINITY;
  float m = fmaxf(e0, e1);
#pragma unroll
  for (int off = 32; off > 0; off >>= 1) m = fmaxf(m, __shfl_xor(m, off));
  float p0 = (lane < deg) ? expf(e0 - m) : 0.f;
  float p1 = (lane + 64 < deg) ? expf(e1 - m) : 0.f;
  float s = p0 + p1;
#pragma unroll
  for (int off = 32; off > 0; off >>= 1) s += __shfl_xor(s, off);
  float inv = 1.f / s;
  att[lane] = p0 * inv;
  att[lane + 64] = p1 * inv;
  jj[lane] = j0;
  jj[lane + 64] = j1;
  __syncthreads();
  if (lane < COUT) {
    float acc = 0.f;
    for (int q = 0; q < deg; ++q) acc += att[q] * H2[(size_t)jj[q] * COUT + lane];
    out[(size_t)i * COUT + lane] = acc;
  }
}

// ---------------------------------------------------------------------------
extern "C" void kernel_launch(void* const* d_in, const int* in_sizes, int n_in,
                              void* d_out, int out_size, void* d_ws, size_t ws_size,
                              hipStream_t stream) {
  const float* x   = (const float*)d_in[0];
  const void*  adj = d_in[1];
  const float* W1  = (const float*)d_in[2];
  const float* a1s = (const float*)d_in[3];
  const float* a1d = (const float*)d_in[4];
  const float* W2  = (const float*)d_in[5];
  const float* a2s = (const float*)d_in[6];
  const float* a2d = (const float*)d_in[7];
  float* out = (float*)d_out;

  char* ws = (char*)d_ws;
  size_t off = 0;
  auto alloc = [&](size_t bytes) -> void* {
    void* p = ws + off;
    off = (off + bytes + 255) & ~(size_t)255;
    return p;
  };
  int*            nbr  = (int*)           alloc((size_t)NN * MAXD * 4);
  int*            cnt  = (int*)           alloc((size_t)NN * 4);
  unsigned short* Xh   = (unsigned short*)alloc((size_t)NN * FIN * 2);
  unsigned short* Xl   = (unsigned short*)alloc((size_t)NN * FIN * 2);
  unsigned short* Wth  = (unsigned short*)alloc((size_t)HC * FIN * 2);
  unsigned short* Wtl  = (unsigned short*)alloc((size_t)HC * FIN * 2);
  float*          H    = (float*)         alloc((size_t)NN * HC * 4);
  float*          fs   = (float*)         alloc((size_t)2 * NN * 4);
  float*          fd   = (float*)         alloc((size_t)2 * NN * 4);
  float*          H1   = (float*)         alloc((size_t)NN * HC * 4);
  float*          H2   = (float*)         alloc((size_t)NN * COUT * 4);
  float*          f2s  = (float*)         alloc((size_t)NN * 4);
  float*          f2d  = (float*)         alloc((size_t)NN * 4);

  hipLaunchKernelGGL(prep_kernel, dim3(4736), dim3(256), 0, stream,
                     x, W1, Xh, Xl, Wth, Wtl, fs, fd);
  hipLaunchKernelGGL(build_csr, dim3(NN), dim3(256), 0, stream, adj, nbr, cnt);
  hipLaunchKernelGGL(gemm1m, dim3(NN / 128, HC / 64), dim3(256), 0, stream,
                     Xh, Xl, Wth, Wtl, a1s, a1d, H, fs, fd);
  hipLaunchKernelGGL(attn1_kernel, dim3(NN), dim3(256), 0, stream, nbr, cnt, H, fs, fd, H1);
  hipLaunchKernelGGL(gemm2_kernel, dim3(NN / 16), dim3(256), 0, stream, H1, W2, a2s, a2d, H2, f2s, f2d);
  hipLaunchKernelGGL(attn2_kernel, dim3(NN), dim3(64), 0, stream, nbr, cnt, H2, f2s, f2d, out);
}

// Round 6
// 438.658 us; speedup vs baseline: 1.0505x; 1.0415x over previous
//
#include <hip/hip_runtime.h>
#include <hip/hip_bf16.h>
#include <math.h>

constexpr int NN   = 8192;   // nodes
constexpr int FIN  = 512;    // input features
constexpr int HC   = 256;    // concat hidden = K(2) * H(128)
constexpr int COUT = 16;     // classes
constexpr int MAXD = 128;    // neighbor cap (avg deg ~33, max ~60)

typedef __attribute__((ext_vector_type(8))) short bf16x8;
typedef __attribute__((ext_vector_type(4))) float f32x4;

__device__ __forceinline__ float lrelu(float x) { return x > 0.f ? x : 0.2f * x; }

__device__ __forceinline__ unsigned short f2bf(float f) {  // RNE f32->bf16
  unsigned u = __float_as_uint(f);
  return (unsigned short)((u + 0x7fffu + ((u >> 16) & 1u)) >> 16);
}
__device__ __forceinline__ float bf2f(unsigned short h) {
  unsigned u = ((unsigned)h) << 16;
  return __uint_as_float(u);
}

// ---------------------------------------------------------------------------
// prep: convert_x (blocks 0..4095), convert_w (4096..4607), zero fs/fd
// (4608..4735).
// ---------------------------------------------------------------------------
__global__ __launch_bounds__(256) void prep_kernel(const float* __restrict__ x,
                                                   const float* __restrict__ W1,
                                                   unsigned short* __restrict__ Xh,
                                                   unsigned short* __restrict__ Xl,
                                                   unsigned short* __restrict__ Wth,
                                                   unsigned short* __restrict__ Wtl,
                                                   float* __restrict__ fs,
                                                   float* __restrict__ fd) {
  int b = blockIdx.x;
  if (b < 4096) {  // x [8192][512] -> split bf16 (4 floats / thread)
    int t = b * 256 + threadIdx.x;
    float4 v = *reinterpret_cast<const float4*>(x + (size_t)t * 4);
    ushort4 hi, lo;
    hi.x = f2bf(v.x); lo.x = f2bf(v.x - bf2f(hi.x));
    hi.y = f2bf(v.y); lo.y = f2bf(v.y - bf2f(hi.y));
    hi.z = f2bf(v.z); lo.z = f2bf(v.z - bf2f(hi.z));
    hi.w = f2bf(v.w); lo.w = f2bf(v.w - bf2f(hi.w));
    *reinterpret_cast<ushort4*>(Xh + (size_t)t * 4) = hi;
    *reinterpret_cast<ushort4*>(Xl + (size_t)t * 4) = lo;
  } else if (b < 4608) {  // W1 [2][512][128] -> transposed-concat split bf16 [n][f]
    int idx = (b - 4096) * 256 + threadIdx.x;  // n*512 + kk
    int n = idx >> 9, kk = idx & 511;
    int k = n >> 7, h = n & 127;
    float v = W1[k * 65536 + kk * 128 + h];
    unsigned short hi = f2bf(v);
    Wth[idx] = hi;
    Wtl[idx] = f2bf(v - bf2f(hi));
  } else {  // zero fs/fd for gemm1m's atomic f-epilogue
    int z = (b - 4608) * 256 + threadIdx.x;  // 0..32767
    if (z < 2 * NN) fs[z] = 0.f;
    else fd[z - 2 * NN] = 0.f;
  }
}

// ---------------------------------------------------------------------------
// H[8192][256] = X @ Wc via split-bf16 MFMA (Ah*Bh + Ah*Bl + Al*Bh).
// Wave tile 32x64; block 128 rows x 64 cols. Fused f-epilogue -> fs/fd.
// ---------------------------------------------------------------------------
__global__ __launch_bounds__(256) void gemm1m(const unsigned short* __restrict__ Xh,
                                              const unsigned short* __restrict__ Xl,
                                              const unsigned short* __restrict__ Bh,
                                              const unsigned short* __restrict__ Bl,
                                              const float* __restrict__ a1s,
                                              const float* __restrict__ a1d,
                                              float* __restrict__ Hout,
                                              float* __restrict__ fs,
                                              float* __restrict__ fd) {
  int wave = threadIdx.x >> 6, lane = threadIdx.x & 63;
  int rowBase = blockIdx.x * 128 + wave * 32;
  int colBase = blockIdx.y * 64;
  int frow = lane & 15;            // A-row / B-col within fragment
  int kchunk = (lane >> 4) * 8;    // k sub-chunk within the 32-wide step
  f32x4 acc[2][4] = {};
  for (int k0 = 0; k0 < FIN; k0 += 32) {
    bf16x8 ah[2], al[2], bh[4], bl[4];
#pragma unroll
    for (int r = 0; r < 2; ++r) {
      size_t off = (size_t)(rowBase + r * 16 + frow) * FIN + k0 + kchunk;
      ah[r] = *reinterpret_cast<const bf16x8*>(Xh + off);
      al[r] = *reinterpret_cast<const bf16x8*>(Xl + off);
    }
#pragma unroll
    for (int c = 0; c < 4; ++c) {
      size_t off = (size_t)(colBase + c * 16 + frow) * FIN + k0 + kchunk;
      bh[c] = *reinterpret_cast<const bf16x8*>(Bh + off);
      bl[c] = *reinterpret_cast<const bf16x8*>(Bl + off);
    }
#pragma unroll
    for (int r = 0; r < 2; ++r)
#pragma unroll
      for (int c = 0; c < 4; ++c) {
        acc[r][c] = __builtin_amdgcn_mfma_f32_16x16x32_bf16(ah[r], bh[c], acc[r][c], 0, 0, 0);
        acc[r][c] = __builtin_amdgcn_mfma_f32_16x16x32_bf16(ah[r], bl[c], acc[r][c], 0, 0, 0);
        acc[r][c] = __builtin_amdgcn_mfma_f32_16x16x32_bf16(al[r], bh[c], acc[r][c], 0, 0, 0);
      }
  }
  // D fragment: col = lane&15, row = (lane>>4)*4 + reg   [m89-verified]
  int dcol = lane & 15, drow4 = (lane >> 4) * 4;
#pragma unroll
  for (int r = 0; r < 2; ++r)
#pragma unroll
    for (int c = 0; c < 4; ++c)
#pragma unroll
      for (int q = 0; q < 4; ++q)
        Hout[(size_t)(rowBase + r * 16 + drow4 + q) * HC + colBase + c * 16 + dcol] =
            acc[r][c][q];
  // fused f_src/f_dst partial reduction (cols colBase..colBase+63, one head)
  int khead = colBase >> 7;
  float as[4], ad[4];
#pragma unroll
  for (int c = 0; c < 4; ++c) {
    as[c] = a1s[colBase + c * 16 + dcol];
    ad[c] = a1d[colBase + c * 16 + dcol];
  }
#pragma unroll
  for (int r = 0; r < 2; ++r)
#pragma unroll
    for (int q = 0; q < 4; ++q) {
      float s = 0.f, d = 0.f;
#pragma unroll
      for (int c = 0; c < 4; ++c) {
        float v = acc[r][c][q];
        s += v * as[c];
        d += v * ad[c];
      }
#pragma unroll
      for (int off = 8; off > 0; off >>= 1) {
        s += __shfl_xor(s, off, 16);
        d += __shfl_xor(d, off, 16);
      }
      if ((lane & 15) == 0) {
        int row = rowBase + r * 16 + drow4 + q;
        atomicAdd(fs + khead * NN + row, s);
        atomicAdd(fd + khead * NN + row, d);
      }
    }
}

// ---------------------------------------------------------------------------
// Layer-1 sparse attention FUSED with adjacency scan. One block per row i:
//   phase 0: detect elem width (diag all-ones; probe rows <2048 keep int32
//            view in-bounds even for uint8 buffer);
//   phase 1: stream adj row (32KB int32 / 8KB uint8) -> neighbor list in LDS
//            (also spilled to nbr/cnt for attn2's reuse);
//   phase 2: scores + masked softmax (exact: exp(NEG_INF-m)==0);
//   phase 3: PV gather from H (L3-served) + ReLU  (relu(elu(z))==relu(z)).
// Removes the separate 268MB build_csr pass from the serial chain.
// ---------------------------------------------------------------------------
__global__ __launch_bounds__(256) void attn1_kernel(const void* __restrict__ adj,
                                                    int* __restrict__ nbr,
                                                    int* __restrict__ cnt,
                                                    const float* __restrict__ H,
                                                    const float* __restrict__ fs,
                                                    const float* __restrict__ fd,
                                                    float* __restrict__ H1) {
  __shared__ float att[2][MAXD];
  __shared__ int jidx[MAXD];
  __shared__ int scnt;
  __shared__ int sflag;
  int i = blockIdx.x;
  int t = threadIdx.x;
  if (t == 0) scnt = 0;
  if (t < 64) {
    size_t idx = (size_t)(t * 32) * (size_t)(NN + 1);
    int v = ((const int*)adj)[idx];
    bool four = (v == 1) || (v == 0x3f800000);
    unsigned long long b = __ballot(four);
    if (t == 0) sflag = (b == ~0ull) ? 1 : 0;
  }
  __syncthreads();
  if (sflag) {  // 4-byte elements (int32 or fp32: nonzero bits == edge)
    const int4* row = reinterpret_cast<const int4*>((const int*)adj + (size_t)i * NN);
#pragma unroll
    for (int rep = 0; rep < 8; ++rep) {
      int vi = rep * 256 + t;
      int4 v = row[vi];
      int base = vi * 4;
      if (v.x) { int p = atomicAdd(&scnt, 1); if (p < MAXD) jidx[p] = base; }
      if (v.y) { int p = atomicAdd(&scnt, 1); if (p < MAXD) jidx[p] = base + 1; }
      if (v.z) { int p = atomicAdd(&scnt, 1); if (p < MAXD) jidx[p] = base + 2; }
      if (v.w) { int p = atomicAdd(&scnt, 1); if (p < MAXD) jidx[p] = base + 3; }
    }
  } else {  // 1-byte elements
    const uint4* row = reinterpret_cast<const uint4*>((const unsigned char*)adj + (size_t)i * NN);
#pragma unroll
    for (int rep = 0; rep < 2; ++rep) {
      int vi = rep * 256 + t;
      uint4 v = row[vi];
      int base = vi * 16;
      unsigned w[4] = {v.x, v.y, v.z, v.w};
#pragma unroll
      for (int q = 0; q < 4; ++q)
#pragma unroll
        for (int bb = 0; bb < 4; ++bb)
          if ((w[q] >> (8 * bb)) & 0xffu) {
            int p = atomicAdd(&scnt, 1);
            if (p < MAXD) jidx[p] = base + q * 4 + bb;
          }
    }
  }
  __syncthreads();
  int deg = scnt < MAXD ? scnt : MAXD;
  if (t == 0) cnt[i] = deg;
  if (t < deg) {
    int j = jidx[t];
    nbr[(size_t)i * MAXD + t] = j;       // for attn2
    att[0][t] = lrelu(fs[i] + fd[j]);
    att[1][t] = lrelu(fs[NN + i] + fd[NN + j]);
  }
  __syncthreads();
  int wave = t >> 6, lane = t & 63;
  if (wave < 2) {
    int k = wave;
    float e0 = (lane < deg) ? att[k][lane] : -INFINITY;
    float e1 = (lane + 64 < deg) ? att[k][lane + 64] : -INFINITY;
    float m = fmaxf(e0, e1);
#pragma unroll
    for (int off = 32; off > 0; off >>= 1) m = fmaxf(m, __shfl_xor(m, off));
    float p0 = (lane < deg) ? expf(e0 - m) : 0.f;
    float p1 = (lane + 64 < deg) ? expf(e1 - m) : 0.f;
    float s = p0 + p1;
#pragma unroll
    for (int off = 32; off > 0; off >>= 1) s += __shfl_xor(s, off);
    float inv = 1.f / s;   // s > 0 guaranteed by self-loop
    if (lane < deg) att[k][lane] = p0 * inv;
    if (lane + 64 < deg) att[k][lane + 64] = p1 * inv;
  }
  __syncthreads();
  int k = t >> 7;
  float acc = 0.f;
  int q = 0;
  for (; q + 4 <= deg; q += 4) {
    float a0 = att[k][q], a1 = att[k][q + 1], a2 = att[k][q + 2], a3 = att[k][q + 3];
    int j0 = jidx[q], j1 = jidx[q + 1], j2 = jidx[q + 2], j3 = jidx[q + 3];
    float g0 = H[(size_t)j0 * HC + t];
    float g1 = H[(size_t)j1 * HC + t];
    float g2 = H[(size_t)j2 * HC + t];
    float g3 = H[(size_t)j3 * HC + t];
    acc += a0 * g0 + a1 * g1 + a2 * g2 + a3 * g3;
  }
  for (; q < deg; ++q) acc += att[k][q] * H[(size_t)jidx[q] * HC + t];
  H1[(size_t)i * HC + t] = fmaxf(acc, 0.f);
}

// ---------------------------------------------------------------------------
// H2[8192][16] = H1[8192][256] @ W2[256][16], fused f2_src/f2_dst reduction.
// ---------------------------------------------------------------------------
__global__ __launch_bounds__(256) void gemm2_kernel(const float* __restrict__ H1,
                                                    const float* __restrict__ W2,
                                                    const float* __restrict__ a2s,
                                                    const float* __restrict__ a2d,
                                                    float* __restrict__ H2,
                                                    float* __restrict__ f2s,
                                                    float* __restrict__ f2d) {
  __shared__ float Ws[HC * COUT];
  int tid = threadIdx.x;
#pragma unroll
  for (int r = 0; r < 16; ++r) Ws[r * 256 + tid] = W2[r * 256 + tid];
  __syncthreads();
  int rg = tid >> 4, c = tid & 15;
  int n = blockIdx.x * 16 + rg;
  const float* h1r = H1 + (size_t)n * HC;
  float acc = 0.f;
#pragma unroll 8
  for (int kk = 0; kk < HC; ++kk) acc += h1r[kk] * Ws[kk * COUT + c];
  H2[(size_t)n * COUT + c] = acc;
  float s = acc * a2s[c];
  float d = acc * a2d[c];
#pragma unroll
  for (int off = 8; off > 0; off >>= 1) {
    s += __shfl_xor(s, off, 16);
    d += __shfl_xor(d, off, 16);
  }
  if (c == 0) { f2s[n] = s; f2d[n] = d; }
}

// ---------------------------------------------------------------------------
// Layer-2 sparse attention; K=1 head so mean == identity. One wave per row.
// ---------------------------------------------------------------------------
__global__ __launch_bounds__(64) void attn2_kernel(const int* __restrict__ nbr,
                                                   const int* __restrict__ cnt,
                                                   const float* __restrict__ H2,
                                                   const float* __restrict__ fs,
                                                   const float* __restrict__ fd,
                                                   float* __restrict__ out) {
  __shared__ float att[MAXD];
  __shared__ int jj[MAXD];
  int i = blockIdx.x;
  int lane = threadIdx.x;
  int deg = cnt[i];
  float fsi = fs[i];
  int j0 = (lane < deg) ? nbr[(size_t)i * MAXD + lane] : 0;
  int j1 = (lane + 64 < deg) ? nbr[(size_t)i * MAXD + lane + 64] : 0;
  float e0 = (lane < deg) ? lrelu(fsi + fd[j0]) : -INFINITY;
  float e1 = (lane + 64 < deg) ? lrelu(fsi + fd[j1]) : -INFINITY;
  float m = fmaxf(e0, e1);
#pragma unroll
  for (int off = 32; off > 0; off >>= 1) m = fmaxf(m, __shfl_xor(m, off));
  float p0 = (lane < deg) ? expf(e0 - m) : 0.f;
  float p1 = (lane + 64 < deg) ? expf(e1 - m) : 0.f;
  float s = p0 + p1;
#pragma unroll
  for (int off = 32; off > 0; off >>= 1) s += __shfl_xor(s, off);
  float inv = 1.f / s;
  att[lane] = p0 * inv;
  att[lane + 64] = p1 * inv;
  jj[lane] = j0;
  jj[lane + 64] = j1;
  __syncthreads();
  if (lane < COUT) {
    float acc = 0.f;
    for (int q = 0; q < deg; ++q) acc += att[q] * H2[(size_t)jj[q] * COUT + lane];
    out[(size_t)i * COUT + lane] = acc;
  }
}

// ---------------------------------------------------------------------------
extern "C" void kernel_launch(void* const* d_in, const int* in_sizes, int n_in,
                              void* d_out, int out_size, void* d_ws, size_t ws_size,
                              hipStream_t stream) {
  const float* x   = (const float*)d_in[0];
  const void*  adj = d_in[1];
  const float* W1  = (const float*)d_in[2];
  const float* a1s = (const float*)d_in[3];
  const float* a1d = (const float*)d_in[4];
  const float* W2  = (const float*)d_in[5];
  const float* a2s = (const float*)d_in[6];
  const float* a2d = (const float*)d_in[7];
  float* out = (float*)d_out;

  char* ws = (char*)d_ws;
  size_t off = 0;
  auto alloc = [&](size_t bytes) -> void* {
    void* p = ws + off;
    off = (off + bytes + 255) & ~(size_t)255;
    return p;
  };
  int*            nbr  = (int*)           alloc((size_t)NN * MAXD * 4);
  int*            cnt  = (int*)           alloc((size_t)NN * 4);
  unsigned short* Xh   = (unsigned short*)alloc((size_t)NN * FIN * 2);
  unsigned short* Xl   = (unsigned short*)alloc((size_t)NN * FIN * 2);
  unsigned short* Wth  = (unsigned short*)alloc((size_t)HC * FIN * 2);
  unsigned short* Wtl  = (unsigned short*)alloc((size_t)HC * FIN * 2);
  float*          H    = (float*)         alloc((size_t)NN * HC * 4);
  float*          fs   = (float*)         alloc((size_t)2 * NN * 4);
  float*          fd   = (float*)         alloc((size_t)2 * NN * 4);
  float*          H1   = (float*)         alloc((size_t)NN * HC * 4);
  float*          H2   = (float*)         alloc((size_t)NN * COUT * 4);
  float*          f2s  = (float*)         alloc((size_t)NN * 4);
  float*          f2d  = (float*)         alloc((size_t)NN * 4);

  hipLaunchKernelGGL(prep_kernel, dim3(4736), dim3(256), 0, stream,
                     x, W1, Xh, Xl, Wth, Wtl, fs, fd);
  hipLaunchKernelGGL(gemm1m, dim3(NN / 128, HC / 64), dim3(256), 0, stream,
                     Xh, Xl, Wth, Wtl, a1s, a1d, H, fs, fd);
  hipLaunchKernelGGL(attn1_kernel, dim3(NN), dim3(256), 0, stream,
                     adj, nbr, cnt, H, fs, fd, H1);
  hipLaunchKernelGGL(gemm2_kernel, dim3(NN / 16), dim3(256), 0, stream,
                     H1, W2, a2s, a2d, H2, f2s, f2d);
  hipLaunchKernelGGL(attn2_kernel, dim3(NN), dim3(64), 0, stream,
                     nbr, cnt, H2, f2s, f2d, out);
}